// Round 6
// baseline (112.385 us; speedup 1.0000x reference)
//
#include <hip/hip_runtime.h>

// WaveletSparsityPrior: 3-level Haar pyramid sparsity loss on (64,1,1024,1024) f32.
// R5 structure (proven 46.7us) with stage-2 fused: each block writes its partial,
// bumps a completion counter; the LAST block re-reads all 2048 partials in fixed
// index order (deterministic sum) and writes d_out[0], overlapping the final
// reduce with the grid drain. Counter zeroed each call via 4-byte hipMemsetAsync.

#define NBLK 2048
#define TILE_STRIDE (NBLK * 256)   // 524288

typedef float floatx4 __attribute__((ext_vector_type(4)));

#define BASE_THR (50.0f / 255.0f)
#define T1P (BASE_THR * 0.5f)
#define T2P (BASE_THR * 2.0f)
#define T3P (BASE_THR * 8.0f)
#define A1P (1.0f / 301989888.0f)
#define A2P (1.0f / 100663296.0f)
#define A3P (1.0f / 25165824.0f)

static __device__ __forceinline__ float band3(float lh, float hl, float hh, float thr) {
    return fminf(fabsf(lh), thr) + fminf(fabsf(hl), thr) + fminf(fabsf(hh), thr);
}

static __device__ __forceinline__ float tile_loss(const float* __restrict__ pred, int tile) {
    const int tx = tile & 127;
    const int ty = (tile >> 7) & 127;
    const int b  = tile >> 14;
    const float* base = pred + ((size_t)b << 20) + ((size_t)ty << 13) + ((size_t)tx << 3);

    float ll1[4][4];
    float s1 = 0.0f, s2 = 0.0f, s3 = 0.0f;

    #pragma unroll
    for (int r = 0; r < 4; ++r) {
        const float* r0 = base + ((size_t)(2 * r) << 10);
        floatx4 a0 = *reinterpret_cast<const floatx4*>(r0);
        floatx4 a1 = *reinterpret_cast<const floatx4*>(r0 + 4);
        floatx4 b0 = *reinterpret_cast<const floatx4*>(r0 + 1024);
        floatx4 b1 = *reinterpret_cast<const floatx4*>(r0 + 1028);
        float lo[8], hi[8];
        #pragma unroll
        for (int k = 0; k < 4; ++k) {
            lo[k]     = a0[k] + b0[k]; hi[k]     = b0[k] - a0[k];
            lo[k + 4] = a1[k] + b1[k]; hi[k + 4] = b1[k] - a1[k];
        }
        #pragma unroll
        for (int c = 0; c < 4; ++c) {
            ll1[r][c] = lo[2 * c] + lo[2 * c + 1];
            float lh = lo[2 * c + 1] - lo[2 * c];
            float hl = hi[2 * c] + hi[2 * c + 1];
            float hh = hi[2 * c + 1] - hi[2 * c];
            s1 += band3(lh, hl, hh, T1P);
        }
    }

    float ll2[2][2];
    #pragma unroll
    for (int r = 0; r < 2; ++r) {
        float lo[4], hi[4];
        #pragma unroll
        for (int c = 0; c < 4; ++c) {
            lo[c] = ll1[2 * r][c] + ll1[2 * r + 1][c];
            hi[c] = ll1[2 * r + 1][c] - ll1[2 * r][c];
        }
        #pragma unroll
        for (int c = 0; c < 2; ++c) {
            ll2[r][c] = lo[2 * c] + lo[2 * c + 1];
            float lh = lo[2 * c + 1] - lo[2 * c];
            float hl = hi[2 * c] + hi[2 * c + 1];
            float hh = hi[2 * c + 1] - hi[2 * c];
            s2 += band3(lh, hl, hh, T2P);
        }
    }

    float lo0 = ll2[0][0] + ll2[1][0];
    float lo1 = ll2[0][1] + ll2[1][1];
    float hi0 = ll2[1][0] - ll2[0][0];
    float hi1 = ll2[1][1] - ll2[0][1];
    s3 = band3(lo1 - lo0, hi0 + hi1, hi1 - hi0, T3P);

    return s1 * A1P + s2 * A2P + s3 * A3P;
}

__global__ __launch_bounds__(256) void wsp_fused(const float* __restrict__ pred,
                                                 float* __restrict__ partial,
                                                 unsigned int* __restrict__ counter,
                                                 float* __restrict__ out) {
    const int tid = blockIdx.x * 256 + threadIdx.x;

    float c = tile_loss(pred, tid) + tile_loss(pred, tid + TILE_STRIDE);

    __shared__ float red[256];
    red[threadIdx.x] = c;
    __syncthreads();
    #pragma unroll
    for (int off = 128; off > 0; off >>= 1) {
        if (threadIdx.x < off) red[threadIdx.x] += red[threadIdx.x + off];
        __syncthreads();
    }

    __shared__ bool last;
    if (threadIdx.x == 0) {
        partial[blockIdx.x] = red[0];
        __threadfence();                       // make partial visible device-wide
        unsigned int old = atomicAdd(counter, 1u);
        last = (old == NBLK - 1);
    }
    __syncthreads();

    if (last) {
        __threadfence();                       // acquire: see all partials
        float s = 0.0f;
        #pragma unroll
        for (int k = 0; k < NBLK / 256; ++k)   // fixed order -> deterministic
            s += partial[threadIdx.x + k * 256];
        red[threadIdx.x] = s;
        __syncthreads();
        #pragma unroll
        for (int off = 128; off > 0; off >>= 1) {
            if (threadIdx.x < off) red[threadIdx.x] += red[threadIdx.x + off];
            __syncthreads();
        }
        if (threadIdx.x == 0) out[0] = red[0];
    }
}

extern "C" void kernel_launch(void* const* d_in, const int* in_sizes, int n_in,
                              void* d_out, int out_size, void* d_ws, size_t ws_size,
                              hipStream_t stream) {
    const float* pred = (const float*)d_in[0];
    float* partial = (float*)d_ws;                       // NBLK*4 = 8 KB
    unsigned int* counter = (unsigned int*)((char*)d_ws + NBLK * sizeof(float));
    float* out = (float*)d_out;

    hipMemsetAsync(counter, 0, sizeof(unsigned int), stream);
    wsp_fused<<<NBLK, 256, 0, stream>>>(pred, partial, counter, out);
}

// Round 7
// 46.885 us; speedup vs baseline: 2.3970x; 2.3970x over previous
//
#include <hip/hip_runtime.h>

// WaveletSparsityPrior: 3-level Haar pyramid sparsity loss on (64,1,1024,1024) f32.
// FINAL (R5-proven, 46.7us): one thread owns one 8x8 tile -> full 3-level pyramid
// in registers; each thread processes TWO tiles via grid-stride -> 2048 blocks =
// exactly one residency round (8 blocks/CU x 256 CU), 32 independent loads in
// flight per thread. 32B lane stride, float4 pairs covering contiguous 2KB per
// wave. All *0.5 scale factors folded into thresholds (coeff* = 2^level x true).
// Stage 2: single-block deterministic reduction of 2048 partials -> d_out[0].
// NOTE (measured): fusing stage-2 via atomics (R4: +25us) or last-block +
// __threadfence (R6: +65us, agent-scope fence = L2 writeback on non-coherent
// XCD L2s) both regress badly. Two-kernel is the right structure on MI355X.

#define NBLK 2048
#define TILE_STRIDE (NBLK * 256)   // 524288

typedef float floatx4 __attribute__((ext_vector_type(4)));

#define BASE_THR (50.0f / 255.0f)
#define T1P (BASE_THR * 0.5f)
#define T2P (BASE_THR * 2.0f)
#define T3P (BASE_THR * 8.0f)
#define A1P (1.0f / 301989888.0f)
#define A2P (1.0f / 100663296.0f)
#define A3P (1.0f / 25165824.0f)

static __device__ __forceinline__ float band3(float lh, float hl, float hh, float thr) {
    return fminf(fabsf(lh), thr) + fminf(fabsf(hl), thr) + fminf(fabsf(hh), thr);
}

static __device__ __forceinline__ float tile_loss(const float* __restrict__ pred, int tile) {
    const int tx = tile & 127;          // tile col
    const int ty = (tile >> 7) & 127;   // tile row
    const int b  = tile >> 14;          // batch
    const float* base = pred + ((size_t)b << 20) + ((size_t)ty << 13) + ((size_t)tx << 3);

    float ll1[4][4];
    float s1 = 0.0f, s2 = 0.0f, s3 = 0.0f;

    // ---- level 1: 8x8 -> 4x4 per band (unscaled) ----
    #pragma unroll
    for (int r = 0; r < 4; ++r) {
        const float* r0 = base + ((size_t)(2 * r) << 10);
        floatx4 a0 = *reinterpret_cast<const floatx4*>(r0);
        floatx4 a1 = *reinterpret_cast<const floatx4*>(r0 + 4);
        floatx4 b0 = *reinterpret_cast<const floatx4*>(r0 + 1024);
        floatx4 b1 = *reinterpret_cast<const floatx4*>(r0 + 1028);
        float lo[8], hi[8];
        #pragma unroll
        for (int k = 0; k < 4; ++k) {
            lo[k]     = a0[k] + b0[k]; hi[k]     = b0[k] - a0[k];
            lo[k + 4] = a1[k] + b1[k]; hi[k + 4] = b1[k] - a1[k];
        }
        #pragma unroll
        for (int c = 0; c < 4; ++c) {
            ll1[r][c] = lo[2 * c] + lo[2 * c + 1];
            float lh = lo[2 * c + 1] - lo[2 * c];
            float hl = hi[2 * c] + hi[2 * c + 1];
            float hh = hi[2 * c + 1] - hi[2 * c];
            s1 += band3(lh, hl, hh, T1P);
        }
    }

    // ---- level 2: 4x4 -> 2x2 per band (unscaled) ----
    float ll2[2][2];
    #pragma unroll
    for (int r = 0; r < 2; ++r) {
        float lo[4], hi[4];
        #pragma unroll
        for (int c = 0; c < 4; ++c) {
            lo[c] = ll1[2 * r][c] + ll1[2 * r + 1][c];
            hi[c] = ll1[2 * r + 1][c] - ll1[2 * r][c];
        }
        #pragma unroll
        for (int c = 0; c < 2; ++c) {
            ll2[r][c] = lo[2 * c] + lo[2 * c + 1];
            float lh = lo[2 * c + 1] - lo[2 * c];
            float hl = hi[2 * c] + hi[2 * c + 1];
            float hh = hi[2 * c + 1] - hi[2 * c];
            s2 += band3(lh, hl, hh, T2P);
        }
    }

    // ---- level 3: 2x2 -> 1x1 per band (unscaled) ----
    float lo0 = ll2[0][0] + ll2[1][0];
    float lo1 = ll2[0][1] + ll2[1][1];
    float hi0 = ll2[1][0] - ll2[0][0];
    float hi1 = ll2[1][1] - ll2[0][1];
    s3 = band3(lo1 - lo0, hi0 + hi1, hi1 - hi0, T3P);

    return s1 * A1P + s2 * A2P + s3 * A3P;
}

__global__ __launch_bounds__(256) void wsp_partial(const float* __restrict__ pred,
                                                   float* __restrict__ partial) {
    const int tid = blockIdx.x * 256 + threadIdx.x;   // 0..524287

    float c = tile_loss(pred, tid) + tile_loss(pred, tid + TILE_STRIDE);

    __shared__ float red[256];
    red[threadIdx.x] = c;
    __syncthreads();
    #pragma unroll
    for (int off = 128; off > 0; off >>= 1) {
        if (threadIdx.x < off) red[threadIdx.x] += red[threadIdx.x + off];
        __syncthreads();
    }
    if (threadIdx.x == 0) partial[blockIdx.x] = red[0];
}

__global__ __launch_bounds__(256) void wsp_reduce(const float* __restrict__ partial,
                                                  float* __restrict__ out) {
    __shared__ float red[256];
    float s = 0.0f;
    for (int i = threadIdx.x; i < NBLK; i += 256) s += partial[i];
    red[threadIdx.x] = s;
    __syncthreads();
    #pragma unroll
    for (int off = 128; off > 0; off >>= 1) {
        if (threadIdx.x < off) red[threadIdx.x] += red[threadIdx.x + off];
        __syncthreads();
    }
    if (threadIdx.x == 0) out[0] = red[0];
}

extern "C" void kernel_launch(void* const* d_in, const int* in_sizes, int n_in,
                              void* d_out, int out_size, void* d_ws, size_t ws_size,
                              hipStream_t stream) {
    const float* pred = (const float*)d_in[0];
    float* partial = (float*)d_ws;           // needs NBLK*4 = 8 KB
    float* out = (float*)d_out;

    wsp_partial<<<NBLK, 256, 0, stream>>>(pred, partial);
    wsp_reduce<<<1, 256, 0, stream>>>(partial, out);
}